// Round 6
// baseline (504.281 us; speedup 1.0000x reference)
//
#include <hip/hip_runtime.h>
#include <stdint.h>

// GoalDecoderLSTM: B=131072 indep LSTM decoders, H=64, E=16, SEQ=30. f32 I/O.
// R12: rational tanh. R11 post-mortem: occupancy 30->44% landed but time flat
// at ~395 -> VALU-WORK floor reached (VALU-busy-time ~255-280us constant over
// R6-R11). Static-vs-measured calibration (R6->R7: 26 ops = 5.1pt VALUBusy)
// shows trans ops cost ~16 cyc issue each -> 48 trans/wave-step = 768 of
// 1354 VALU cyc = 57%. Fix: cut trans 6->4/elem. Both tanh paths (e^{2g},
// e^{2c'}) replaced by clamped [7/6] Pade rational
//   tanh(x) ~= x(t^3+378t^2+17325t+135135)/(28t^3+3150t^2+62370t+135135),
// t=x^2, |x|<=4.7, global err ~1e-4 < f16 h-storage ulp (5e-4) -> absmax
// unchanged. g-gate prescale now 1.0 (raw); sigmoids keep exact exp2.
// Common-denominator + pair-rcp structure preserved:
//   c' = (c(1+A)Qg + g*Pg*(1+F)) / ((1+A)(1+F)Qg), one paired rcp;
//   h  = c'*Pc / (Qc*(1+C)), one paired rcp. Den bound ~1.6e15, pair 2.6e30,
// f32-safe. Everything else identical to R11 (weights in LDS, 512-thr
// blocks, 4 waves/SIMD, swizzled hbuf, all-quad rel, lrelu rank-2 fold).

#define B_TOT 131072
#define SEQL 30
#define NT 4  // tiles per 512-thread block; NT_eff = 2 per wave

typedef _Float16 f16x8 __attribute__((ext_vector_type(8)));
typedef _Float16 f16x2 __attribute__((ext_vector_type(2)));
typedef float f32x4 __attribute__((ext_vector_type(4)));
typedef float f32x2 __attribute__((ext_vector_type(2)));

__device__ __forceinline__ float fexp2(float x) {
#if __has_builtin(__builtin_amdgcn_exp2f)
  return __builtin_amdgcn_exp2f(x);
#else
  return exp2f(x);
#endif
}
__device__ __forceinline__ float frcp(float x) {
#if __has_builtin(__builtin_amdgcn_rcpf)
  return __builtin_amdgcn_rcpf(x);
#else
  return 1.0f / x;
#endif
}

// ws layout (floats): [0:64] M0, [64:128] M1,
// [128..135] Sx0,Sx1,Sy0,Sy1,Sb0,Sb1,C00,C01.
__global__ void setup_consts(const float* __restrict__ Wgoal,
                             const float* __restrict__ bgoal,
                             const float* __restrict__ Wh2p,
                             const float* __restrict__ bh2p,
                             const float* __restrict__ Wabs,
                             const float* __restrict__ babs,
                             float* __restrict__ wsf) {
  const int tid = threadIdx.x;
  const int wv = tid >> 6;
  const int lane = tid & 63;
  if (wv == 0) {
    const int k = lane;
    float s0 = 0.f, s1 = 0.f;
#pragma unroll 8
    for (int jj = 0; jj < 64; ++jj) {
      float wg = Wgoal[jj * 64 + k];
      s0 += wg * Wh2p[128 + jj];
      s1 += wg * Wh2p[320 + jj];
    }
    wsf[k] = s0;
    wsf[64 + k] = s1;
  } else {
    const int i = lane >> 3, sub = lane & 7;
    const int p = i & 1, grp = i >> 1;
    float s = 0.f;
#pragma unroll
    for (int t = 0; t < 8; ++t) {
      int j = sub * 8 + t;
      float wv_ = (grp < 3) ? Wh2p[p * 192 + 64 + j] : Wh2p[p * 192 + 128 + j];
      float av = (grp == 0)   ? Wabs[j * 2 + 0]
                 : (grp == 1) ? Wabs[j * 2 + 1]
                 : (grp == 2) ? babs[j]
                              : bgoal[j];
      s += av * wv_;
    }
    s += __shfl_xor(s, 1, 64);
    s += __shfl_xor(s, 2, 64);
    s += __shfl_xor(s, 4, 64);
    if (sub == 0) {
      if (grp == 2) s += bh2p[p];
      wsf[128 + i] = s;
    }
  }
}

__global__ __launch_bounds__(512, 4) void lstm_mfma(
    const float* __restrict__ tabs, const float* __restrict__ trel,
    const float* __restrict__ h0, const float* __restrict__ c0,
    const float* __restrict__ goals, const float* __restrict__ Wih,
    const float* __restrict__ Whh, const float* __restrict__ bih,
    const float* __restrict__ bhh, const float* __restrict__ Wse,
    const float* __restrict__ bse, const float* __restrict__ Wh2p,
    const float* __restrict__ wsf, float* __restrict__ outp) {
  const int lane = threadIdx.x & 63;
  const int w = threadIdx.x >> 6;  // 0..7
  const int wsl = w & 3;           // hidden slice [16wsl, 16wsl+16)
  const int tp = w >> 2;           // tile-pair: tiles {2tp, 2tp+1}
  const int q = lane >> 4;
  const int n = lane & 15;
  const int pm = n & 3;  // replicated rel/goal A-row selector
  const int hs = 16 * wsl;
  const int bbase = blockIdx.x * (16 * NT);

  // LDS: prescaled weights (shared by all 8 waves) + swizzled h dbuf = 64KB.
  __shared__ __align__(16) _Float16 whh[4 * 64 * 64];  // [g*64+h][k0..63]
  __shared__ __align__(16) _Float16 wx[4 * 64 * 32];   // [g*64+h][kx0..31]
  __shared__ __align__(16) _Float16 hbuf[2 * NT * 16 * 64];  // [db][t][row][64]

  const float SI = -1.4426950408889634f;

  // ---- weight LDS init (once). i,f,o prescaled by -log2e (exp2-ready);
  // g RAW (rational tanh). XOR slot swizzle: slot ^= row&7 (whh) / row&3 (wx).
  for (int idx = threadIdx.x; idx < 4 * 64 * 64; idx += 512) {
    const int r = idx >> 6, k = idx & 63;
    const float sc = ((r >> 6) == 2) ? 1.0f : SI;
    const int slot = (k >> 3) ^ (r & 7);
    whh[r * 64 + slot * 8 + (k & 7)] = (_Float16)(sc * Whh[r * 64 + k]);
  }
  if (threadIdx.x < 256) {
    const int r = threadIdx.x;  // g*64 + h
    const float sc = ((r >> 6) == 2) ? 1.0f : SI;
    float bfold = 0.f, m20 = 0.f, m21 = 0.f;
#pragma unroll
    for (int k = 0; k < 16; ++k) {
      float wik = Wih[r * 16 + k];
      bfold += bse[k] * wik;
      m20 += Wse[k * 2 + 0] * wik;
      m21 += Wse[k * 2 + 1] * wik;
    }
    const float bias = sc * (bih[r] + bhh[r] + 0.505f * bfold);
#pragma unroll
    for (int kx = 0; kx < 32; ++kx) {
      float v;
      if (kx < 16)
        v = sc * Wih[r * 16 + kx];  // pairs with 0.495|u|
      else if (kx == 16)
        v = bias;  // pairs with A=1
      else if (kx == 17)
        v = sc * 0.505f * m20;  // pairs with A=rel0
      else if (kx == 18)
        v = sc * 0.505f * m21;  // pairs with A=rel1
      else
        v = 0.f;
      const int slot = (kx >> 3) ^ (r & 3);
      wx[r * 32 + slot * 8 + (kx & 7)] = (_Float16)v;
    }
  }

  // ---- rel projection A-frags, replicated rows m&3<2 (registers) ----
  f16x8 awp0, awp1;
#pragma unroll
  for (int j = 0; j < 8; ++j) {
    float v0 = (pm < 2) ? Wh2p[pm * 192 + q * 8 + j] : 0.f;
    float v1 = (pm < 2) ? Wh2p[pm * 192 + 32 + q * 8 + j] : 0.f;
    awp0[j] = (_Float16)v0;
    awp1[j] = (_Float16)v1;
  }
  const float Sx0 = wsf[128], Sx1 = wsf[129];
  const float Sy0 = wsf[130], Sy1 = wsf[131];

  // ---- Wse consts (pre-scaled by 0.495) as pk pairs ----
  f16x2 wsaP[4], wsbP[4], bscP[4];
  const uint32_t xmask = (q < 2) ? 0x7FFF7FFFu : 0xFFFFFFFFu;
#pragma unroll
  for (int jj = 0; jj < 4; ++jj) {
    f16x2 z = f16x2{(_Float16)0.f, (_Float16)0.f};
    if (q < 2) {
      int kx = q * 8 + 2 * jj;
      wsaP[jj] = f16x2{(_Float16)(0.495f * Wse[kx * 2 + 0]),
                       (_Float16)(0.495f * Wse[kx * 2 + 2])};
      wsbP[jj] = f16x2{(_Float16)(0.495f * Wse[kx * 2 + 1]),
                       (_Float16)(0.495f * Wse[kx * 2 + 3])};
      bscP[jj] = f16x2{(_Float16)(0.495f * bse[kx]),
                       (_Float16)(0.495f * bse[kx + 1])};
    } else if (q == 2 && jj == 0) {
      wsaP[jj] = f16x2{(_Float16)0.f, (_Float16)1.f};  // t = {1, r0}
      wsbP[jj] = z;
      bscP[jj] = f16x2{(_Float16)1.f, (_Float16)0.f};
    } else if (q == 2 && jj == 1) {
      wsaP[jj] = z;  // t = {r1, 0}
      wsbP[jj] = f16x2{(_Float16)1.f, (_Float16)0.f};
      bscP[jj] = z;
    } else {
      wsaP[jj] = z;
      wsbP[jj] = z;
      bscP[jj] = z;
    }
  }

  auto build_x = [&](float r0f, float r1f) -> f16x8 {
    f16x2 r0h = f16x2{(_Float16)r0f, (_Float16)r0f};
    f16x2 r1h = f16x2{(_Float16)r1f, (_Float16)r1f};
    f16x8 xr;
#pragma unroll
    for (int jj = 0; jj < 4; ++jj) {
      f16x2 t = r0h * wsaP[jj] + (r1h * wsbP[jj] + bscP[jj]);
      uint32_t tu = __builtin_bit_cast(uint32_t, t) & xmask;
      f16x2 lr = __builtin_bit_cast(f16x2, tu);
      xr[2 * jj] = lr[0];
      xr[2 * jj + 1] = lr[1];
    }
    return xr;
  };

  const f32x4 zC = {0.f, 0.f, 0.f, 0.f};

  // ---- per-tile state (2 local tiles: global tile = 2*tp + u) ----
  float Gg0[2], Gg1[2];
  float ax[2], ay[2], cst[2][4];
  f16x8 xf[2];
  {
    f16x8 aM0, aM1;
#pragma unroll
    for (int j = 0; j < 8; ++j) {
      int k = q * 8 + j;
      aM0[j] = (_Float16)((pm < 2) ? wsf[pm * 64 + k] : 0.f);
      aM1[j] = (_Float16)((pm < 2) ? wsf[pm * 64 + 32 + k] : 0.f);
    }
    const float Sb0 = wsf[132] + wsf[134];
    const float Sb1 = wsf[133] + wsf[135];
#pragma unroll
    for (int u = 0; u < 2; ++u) {
      const int tg = 2 * tp + u;
      const int bb = bbase + 16 * tg;
      f16x8 bg0, bg1;
#pragma unroll
      for (int j = 0; j < 8; ++j) {
        int k = q * 8 + j;
        bg0[j] = (_Float16)goals[(bb + n) * 64 + k];
        bg1[j] = (_Float16)goals[(bb + n) * 64 + 32 + k];
      }
      f32x4 Ga = __builtin_amdgcn_mfma_f32_16x16x32_f16(aM0, bg0, zC, 0, 0, 0);
      Ga = __builtin_amdgcn_mfma_f32_16x16x32_f16(aM1, bg1, Ga, 0, 0, 0);
      Gg0[u] = Ga[0] + Sb0;
      Gg1[u] = Ga[1] + Sb1;

      ax[u] = tabs[(bb + n) * 2 + 0];
      ay[u] = tabs[(bb + n) * 2 + 1];
      // h0 into swizzled hbuf rows (this wave's hidden slice, its tiles)
      const int cslot = (hs + n) >> 3, cin = n & 7;
#pragma unroll
      for (int r = 0; r < 4; ++r) {
        const int row = 4 * q + r;
        const int b = bb + row;
        cst[u][r] = c0[b * 64 + hs + n];
        hbuf[tg * 1024 + row * 64 + ((cslot ^ (row & 7)) << 3) + cin] =
            (_Float16)h0[b * 64 + hs + n];
      }
      xf[u] = build_x(trel[(bb + n) * 2 + 0], trel[(bb + n) * 2 + 1]);
    }
  }

  // ---- precomputed swizzled offsets ----
  const int ro0 = n * 64 + ((q ^ (n & 7)) << 3);
  const int ro1 = n * 64 + (((4 + q) ^ (n & 7)) << 3);
  const int hb = (hs + n) * 64;
  const int sl0 = (q ^ (n & 7)) << 3;
  const int sl1 = (((4 + q) ^ (n & 7))) << 3;
  const int xb = (hs + n) * 32 + ((q ^ (n & 3)) << 3);
  const int wslot = (hs + n) >> 3, wcin = n & 7;

  // tanh(x) ~= x*(t^3+378t^2+17325t+135135)/(28t^3+3150t^2+62370t+135135)
  const float TA1 = 378.f, TA2 = 17325.f, TA3 = 135135.f;
  const float TB0 = 28.f, TB1 = 3150.f, TB2 = 62370.f;
  const float CLP = 4.7f;

  int poff = 0;  // dbuf toggle: 0 <-> 4096
  for (int s = 0; s <= SEQL; ++s) {
    __syncthreads();  // hbuf[poff] holds h_s; weights ready (s=0)
    f16x8 ah0[2], ah1[2];
#pragma unroll
    for (int u = 0; u < 2; ++u) {
      const int tb = poff + (2 * tp + u) * 1024;
      ah0[u] = *(const f16x8*)(hbuf + tb + ro0);
      ah1[u] = *(const f16x8*)(hbuf + tb + ro1);
    }

    if (s > 0) {
      // rel_{s-1}: D[p][batch], regs 0,1 valid on every quad -> lane-local.
#pragma unroll
      for (int u = 0; u < 2; ++u) {
        f32x4 p = __builtin_amdgcn_mfma_f32_16x16x32_f16(awp0, ah0[u], zC,
                                                         0, 0, 0);
        p = __builtin_amdgcn_mfma_f32_16x16x32_f16(awp1, ah1[u], p, 0, 0, 0);
        float u0 = p[0] + Gg0[u] + fmaf(ax[u], Sx0, ay[u] * Sy0);
        float u1 = p[1] + Gg1[u] + fmaf(ax[u], Sx1, ay[u] * Sy1);
        ax[u] += u0;
        ay[u] += u1;
        if (wsl == u && lane < 16) {
          float2 v;
          v.x = u0;
          v.y = u1;
          ((float2*)outp)[(size_t)(s - 1) * B_TOT + bbase + 16 * (2 * tp + u) +
                          lane] = v;
        }
        xf[u] = build_x(u0, u1);
      }
    }

    if (s < SEQL) {
      f32x4 acc[2][4];
#pragma unroll
      for (int g = 0; g < 4; ++g) {
        // gate weight frags from LDS (shared across tiles & waves)
        const f16x8 w0 = *(const f16x8*)(whh + g * 4096 + hb + sl0);
        const f16x8 w1 = *(const f16x8*)(whh + g * 4096 + hb + sl1);
        const f16x8 w2 = *(const f16x8*)(wx + g * 2048 + xb);
#pragma unroll
        for (int u = 0; u < 2; ++u) {
          f32x4 a = __builtin_amdgcn_mfma_f32_16x16x32_f16(ah0[u], w0, zC,
                                                           0, 0, 0);
          a = __builtin_amdgcn_mfma_f32_16x16x32_f16(ah1[u], w1, a, 0, 0, 0);
          a = __builtin_amdgcn_mfma_f32_16x16x32_f16(xf[u], w2, a, 0, 0, 0);
          acc[u][g] = a;
        }
      }
#pragma unroll
      for (int u = 0; u < 2; ++u) {
        _Float16* hw = hbuf + (poff ^ 4096) + (2 * tp + u) * 1024;
        // acc0=-i*log2e, acc1=-f*log2e, acc2=g RAW, acc3=-o*log2e.
        // A=e^{-i}, F=e^{-f}, C=e^{-o}; tanh via Pade rational, pair-rcp.
#pragma unroll
        for (int pr = 0; pr < 2; ++pr) {
          const int ra = 2 * pr, rb = 2 * pr + 1;
          f32x2 Av = {fexp2(acc[u][0][ra]), fexp2(acc[u][0][rb])};
          f32x2 Fv = {fexp2(acc[u][1][ra]), fexp2(acc[u][1][rb])};
          f32x2 Cv = {fexp2(acc[u][3][ra]), fexp2(acc[u][3][rb])};
          const f32x2 one = {1.f, 1.f};
          // tanh(g) rational
          f32x2 gg = {fminf(CLP, fmaxf(-CLP, acc[u][2][ra])),
                      fminf(CLP, fmaxf(-CLP, acc[u][2][rb]))};
          f32x2 tg = gg * gg;
          f32x2 npg = (tg + TA1) * tg + TA2;
          npg = npg * tg + TA3;
          f32x2 Tn = gg * npg;  // tanh(g) numerator (x*P)
          f32x2 dpg = (tg * TB0 + TB1) * tg + TB2;
          dpg = dpg * tg + TA3;  // tanh(g) denominator Q
          // c' = (c(1+A)Qg + Tn(1+F)) / ((1+A)(1+F)Qg), one paired rcp
          f32x2 t1 = Av + one;
          f32x2 t3 = Fv + one;
          f32x2 u1v = t1 * dpg;
          f32x2 cs = {cst[u][ra], cst[u][rb]};
          f32x2 num = cs * u1v + Tn * t3;
          f32x2 den = u1v * t3;
          float Rc = frcp(den[0] * den[1]);
          float cc0 = num[0] * den[1] * Rc;
          float cc1 = num[1] * den[0] * Rc;
          cst[u][ra] = cc0;
          cst[u][rb] = cc1;
          // h = tanh(c') * sig(o) = (c'*Pc) / (Qc*(1+C)), one paired rcp
          f32x2 cp = {fminf(CLP, fmaxf(-CLP, cc0)),
                      fminf(CLP, fmaxf(-CLP, cc1))};
          f32x2 tc = cp * cp;
          f32x2 npc = (tc + TA1) * tc + TA2;
          npc = npc * tc + TA3;
          f32x2 Tc = cp * npc;
          f32x2 dpc = (tc * TB0 + TB1) * tc + TB2;
          dpc = dpc * tc + TA3;
          f32x2 t5 = Cv + one;
          f32x2 hden = dpc * t5;
          float Rh = frcp(hden[0] * hden[1]);
          float h0v = Tc[0] * hden[1] * Rh;
          float h1v = Tc[1] * hden[0] * Rh;
          const int rowa = 4 * q + ra, rowb = 4 * q + rb;
          hw[rowa * 64 + ((wslot ^ (rowa & 7)) << 3) + wcin] = (_Float16)h0v;
          hw[rowb * 64 + ((wslot ^ (rowb & 7)) << 3) + wcin] = (_Float16)h1v;
        }
      }
      poff ^= 4096;
    }
  }
}

extern "C" void kernel_launch(void* const* d_in, const int* in_sizes, int n_in,
                              void* d_out, int out_size, void* d_ws,
                              size_t ws_size, hipStream_t stream) {
  (void)in_sizes; (void)n_in; (void)out_size; (void)ws_size;
  const float* tabs  = (const float*)d_in[0];
  const float* trel  = (const float*)d_in[1];
  const float* h0    = (const float*)d_in[2];
  const float* c0    = (const float*)d_in[3];
  const float* goals = (const float*)d_in[4];
  const float* Wih   = (const float*)d_in[5];
  const float* Whh   = (const float*)d_in[6];
  const float* bih   = (const float*)d_in[7];
  const float* bhh   = (const float*)d_in[8];
  const float* Wse   = (const float*)d_in[9];
  const float* bse   = (const float*)d_in[10];
  const float* Wh2p  = (const float*)d_in[11];
  const float* bh2p  = (const float*)d_in[12];
  const float* Wgoal = (const float*)d_in[13];
  const float* bgoal = (const float*)d_in[14];
  const float* Wabs  = (const float*)d_in[15];
  const float* babs  = (const float*)d_in[16];
  float* wsf = (float*)d_ws;

  setup_consts<<<dim3(1), dim3(128), 0, stream>>>(Wgoal, bgoal, Wh2p, bh2p,
                                                  Wabs, babs, wsf);
  lstm_mfma<<<dim3(B_TOT / (16 * NT)), dim3(512), 0, stream>>>(
      tabs, trel, h0, c0, goals, Wih, Whh, bih, bhh, Wse, bse, Wh2p, wsf,
      (float*)d_out);
}

// Round 7
// 447.377 us; speedup vs baseline: 1.1272x; 1.1272x over previous
//
#include <hip/hip_runtime.h>
#include <stdint.h>

// GoalDecoderLSTM: B=131072 indep LSTM decoders, H=64, E=16, SEQ=30. f32 I/O.
// R13: barrier-free autonomous waves. R12 post-mortem: rational tanh ADDED
// ~30us VALU work (exp2 is cheap, ~4-8cyc; the 16cyc model was wrong) ->
// REVERTED to R11's exp2 nonlinearity. Remaining target: ~117us (30%) idle
// from the per-step __syncthreads() h-exchange. Fix: one wave owns one WHOLE
// tile (16 batches x all 64 hidden). h lives in a per-wave private 2KB LDS
// scratch (write h_{s+1}, read next step; same-wave lgkmcnt ordering) ->
// ZERO barriers in the 30-step loop. Per step per wave: rel (2 MFMA, now 1x
// instead of 4x-redundant) + 4 hidden-slices x {12 weight ds_read_b128 from
// block-shared LDS + 12 MFMA + exp2 nonlinearity}. acc peak 16 regs; c-state
// 16 regs/lane. LDS = 32K whh + 16K wx + 8x2K scratch = 64KB exactly ->
// 2 blocks/CU, 4 independent waves/SIMD.
// Kept: prescaled gate weights (-log2e / +2log2e, exp2-ready), lrelu rank-2
// fold (wx k-slots 16..18), all-quad rel, f32x2 nonlinearity + pair-rcp,
// XOR 16B-chunk swizzle on scratch & weights.

#define B_TOT 131072
#define SEQL 30
#define WPB 8  // waves per block = tiles per block

typedef _Float16 f16x8 __attribute__((ext_vector_type(8)));
typedef _Float16 f16x2 __attribute__((ext_vector_type(2)));
typedef float f32x4 __attribute__((ext_vector_type(4)));
typedef float f32x2 __attribute__((ext_vector_type(2)));

__device__ __forceinline__ float fexp2(float x) {
#if __has_builtin(__builtin_amdgcn_exp2f)
  return __builtin_amdgcn_exp2f(x);
#else
  return exp2f(x);
#endif
}
__device__ __forceinline__ float frcp(float x) {
#if __has_builtin(__builtin_amdgcn_rcpf)
  return __builtin_amdgcn_rcpf(x);
#else
  return 1.0f / x;
#endif
}

// ws layout (floats): [0:64] M0, [64:128] M1,
// [128..135] Sx0,Sx1,Sy0,Sy1,Sb0,Sb1,C00,C01.
__global__ void setup_consts(const float* __restrict__ Wgoal,
                             const float* __restrict__ bgoal,
                             const float* __restrict__ Wh2p,
                             const float* __restrict__ bh2p,
                             const float* __restrict__ Wabs,
                             const float* __restrict__ babs,
                             float* __restrict__ wsf) {
  const int tid = threadIdx.x;
  const int wv = tid >> 6;
  const int lane = tid & 63;
  if (wv == 0) {
    const int k = lane;
    float s0 = 0.f, s1 = 0.f;
#pragma unroll 8
    for (int jj = 0; jj < 64; ++jj) {
      float wg = Wgoal[jj * 64 + k];
      s0 += wg * Wh2p[128 + jj];
      s1 += wg * Wh2p[320 + jj];
    }
    wsf[k] = s0;
    wsf[64 + k] = s1;
  } else {
    const int i = lane >> 3, sub = lane & 7;
    const int p = i & 1, grp = i >> 1;
    float s = 0.f;
#pragma unroll
    for (int t = 0; t < 8; ++t) {
      int j = sub * 8 + t;
      float wv_ = (grp < 3) ? Wh2p[p * 192 + 64 + j] : Wh2p[p * 192 + 128 + j];
      float av = (grp == 0)   ? Wabs[j * 2 + 0]
                 : (grp == 1) ? Wabs[j * 2 + 1]
                 : (grp == 2) ? babs[j]
                              : bgoal[j];
      s += av * wv_;
    }
    s += __shfl_xor(s, 1, 64);
    s += __shfl_xor(s, 2, 64);
    s += __shfl_xor(s, 4, 64);
    if (sub == 0) {
      if (grp == 2) s += bh2p[p];
      wsf[128 + i] = s;
    }
  }
}

__global__ __launch_bounds__(512, 4) void lstm_mfma(
    const float* __restrict__ tabs, const float* __restrict__ trel,
    const float* __restrict__ h0, const float* __restrict__ c0,
    const float* __restrict__ goals, const float* __restrict__ Wih,
    const float* __restrict__ Whh, const float* __restrict__ bih,
    const float* __restrict__ bhh, const float* __restrict__ Wse,
    const float* __restrict__ bse, const float* __restrict__ Wh2p,
    const float* __restrict__ wsf, float* __restrict__ outp) {
  const int lane = threadIdx.x & 63;
  const int w = threadIdx.x >> 6;  // wave = tile owner (0..7)
  const int q = lane >> 4;
  const int n = lane & 15;
  const int pm = n & 3;  // replicated rel/goal A-row selector
  const int bb = blockIdx.x * (16 * WPB) + 16 * w;  // this wave's batch base

  // LDS: block-shared prescaled weights + per-wave private h scratch = 64KB.
  __shared__ __align__(16) _Float16 whh[4 * 64 * 64];  // [g*64+h][k0..63]
  __shared__ __align__(16) _Float16 wx[4 * 64 * 32];   // [g*64+h][kx0..31]
  __shared__ __align__(16) _Float16 hscr[WPB * 16 * 64];  // [wave][batch][h]

  const float SI = -1.4426950408889634f;
  const float SG = 2.8853900817779268f;

  // ---- weight LDS init (once). i,f,o prescaled by -log2e; g by +2log2e
  // (accs exp2-ready). XOR 16B-chunk swizzle: slot ^= row&7 (whh) / row&3
  // (wx) so per-quad frag reads spread banks.
  for (int idx = threadIdx.x; idx < 4 * 64 * 64; idx += 512) {
    const int r = idx >> 6, k = idx & 63;
    const float sc = ((r >> 6) == 2) ? SG : SI;
    const int slot = (k >> 3) ^ (r & 7);
    whh[r * 64 + slot * 8 + (k & 7)] = (_Float16)(sc * Whh[r * 64 + k]);
  }
  if (threadIdx.x < 256) {
    const int r = threadIdx.x;  // g*64 + h
    const float sc = ((r >> 6) == 2) ? SG : SI;
    float bfold = 0.f, m20 = 0.f, m21 = 0.f;
#pragma unroll
    for (int k = 0; k < 16; ++k) {
      float wik = Wih[r * 16 + k];
      bfold += bse[k] * wik;
      m20 += Wse[k * 2 + 0] * wik;
      m21 += Wse[k * 2 + 1] * wik;
    }
    const float bias = sc * (bih[r] + bhh[r] + 0.505f * bfold);
#pragma unroll
    for (int kx = 0; kx < 32; ++kx) {
      float v;
      if (kx < 16)
        v = sc * Wih[r * 16 + kx];  // pairs with 0.495|u|
      else if (kx == 16)
        v = bias;  // pairs with A=1
      else if (kx == 17)
        v = sc * 0.505f * m20;  // pairs with A=rel0
      else if (kx == 18)
        v = sc * 0.505f * m21;  // pairs with A=rel1
      else
        v = 0.f;
      const int slot = (kx >> 3) ^ (r & 3);
      wx[r * 32 + slot * 8 + (kx & 7)] = (_Float16)v;
    }
  }

  // ---- rel projection A-frags, replicated rows m&3<2 (registers) ----
  f16x8 awp0, awp1;
#pragma unroll
  for (int j = 0; j < 8; ++j) {
    float v0 = (pm < 2) ? Wh2p[pm * 192 + q * 8 + j] : 0.f;
    float v1 = (pm < 2) ? Wh2p[pm * 192 + 32 + q * 8 + j] : 0.f;
    awp0[j] = (_Float16)v0;
    awp1[j] = (_Float16)v1;
  }
  const float Sx0 = wsf[128], Sx1 = wsf[129];
  const float Sy0 = wsf[130], Sy1 = wsf[131];

  // ---- Wse consts (pre-scaled by 0.495) as pk pairs ----
  f16x2 wsaP[4], wsbP[4], bscP[4];
  const uint32_t xmask = (q < 2) ? 0x7FFF7FFFu : 0xFFFFFFFFu;
#pragma unroll
  for (int jj = 0; jj < 4; ++jj) {
    f16x2 z = f16x2{(_Float16)0.f, (_Float16)0.f};
    if (q < 2) {
      int kx = q * 8 + 2 * jj;
      wsaP[jj] = f16x2{(_Float16)(0.495f * Wse[kx * 2 + 0]),
                       (_Float16)(0.495f * Wse[kx * 2 + 2])};
      wsbP[jj] = f16x2{(_Float16)(0.495f * Wse[kx * 2 + 1]),
                       (_Float16)(0.495f * Wse[kx * 2 + 3])};
      bscP[jj] = f16x2{(_Float16)(0.495f * bse[kx]),
                       (_Float16)(0.495f * bse[kx + 1])};
    } else if (q == 2 && jj == 0) {
      wsaP[jj] = f16x2{(_Float16)0.f, (_Float16)1.f};  // t = {1, r0}
      wsbP[jj] = z;
      bscP[jj] = f16x2{(_Float16)1.f, (_Float16)0.f};
    } else if (q == 2 && jj == 1) {
      wsaP[jj] = z;  // t = {r1, 0}
      wsbP[jj] = f16x2{(_Float16)1.f, (_Float16)0.f};
      bscP[jj] = z;
    } else {
      wsaP[jj] = z;
      wsbP[jj] = z;
      bscP[jj] = z;
    }
  }

  auto build_x = [&](float r0f, float r1f) -> f16x8 {
    f16x2 r0h = f16x2{(_Float16)r0f, (_Float16)r0f};
    f16x2 r1h = f16x2{(_Float16)r1f, (_Float16)r1f};
    f16x8 xr;
#pragma unroll
    for (int jj = 0; jj < 4; ++jj) {
      f16x2 t = r0h * wsaP[jj] + (r1h * wsbP[jj] + bscP[jj]);
      uint32_t tu = __builtin_bit_cast(uint32_t, t) & xmask;
      f16x2 lr = __builtin_bit_cast(f16x2, tu);
      xr[2 * jj] = lr[0];
      xr[2 * jj + 1] = lr[1];
    }
    return xr;
  };

  const f32x4 zC = {0.f, 0.f, 0.f, 0.f};
  const int wbase = w * 1024;  // this wave's private scratch (f16 units)

  // ---- per-wave tile state: goal consts, traj, c-state (16 f32/lane) ----
  float Gg0, Gg1, ax, ay;
  float cst[4][4];  // [slice m][r] = c[batch 4q+r][hidden 16m+n]
  f16x8 xf;
  {
    f16x8 aM0, aM1, bg0, bg1;
#pragma unroll
    for (int j = 0; j < 8; ++j) {
      int k = q * 8 + j;
      aM0[j] = (_Float16)((pm < 2) ? wsf[pm * 64 + k] : 0.f);
      aM1[j] = (_Float16)((pm < 2) ? wsf[pm * 64 + 32 + k] : 0.f);
      bg0[j] = (_Float16)goals[(bb + n) * 64 + k];
      bg1[j] = (_Float16)goals[(bb + n) * 64 + 32 + k];
    }
    f32x4 Ga = __builtin_amdgcn_mfma_f32_16x16x32_f16(aM0, bg0, zC, 0, 0, 0);
    Ga = __builtin_amdgcn_mfma_f32_16x16x32_f16(aM1, bg1, Ga, 0, 0, 0);
    Gg0 = Ga[0] + wsf[132] + wsf[134];
    Gg1 = Ga[1] + wsf[133] + wsf[135];

    ax = tabs[(bb + n) * 2 + 0];
    ay = tabs[(bb + n) * 2 + 1];
    // h0/c0: 16 elems/lane (batch 4q+r, hidden 16m+n); swizzled scratch.
#pragma unroll
    for (int m = 0; m < 4; ++m) {
      const int c16 = 2 * m + (n >> 3);
#pragma unroll
      for (int r = 0; r < 4; ++r) {
        const int br = 4 * q + r;
        cst[m][r] = c0[(bb + br) * 64 + 16 * m + n];
        hscr[wbase + br * 64 + ((c16 ^ (br & 7)) << 3) + (n & 7)] =
            (_Float16)h0[(bb + br) * 64 + 16 * m + n];
      }
    }
    xf = build_x(trel[(bb + n) * 2 + 0], trel[(bb + n) * 2 + 1]);
  }

  __syncthreads();  // weights staged; ONLY barrier before/inside the loop

  // ---- scratch read offsets (A-frag layout, 16B-chunk XOR swizzle) ----
  const int ro0 = wbase + n * 64 + ((q ^ (n & 7)) << 3);
  const int ro1 = wbase + n * 64 + (((4 + q) ^ (n & 7)) << 3);
  const int sl0 = (q ^ (n & 7)) << 3;
  const int sl1 = ((4 + q) ^ (n & 7)) << 3;
  const int xsl = (q ^ (n & 3)) << 3;
  const float K2 = 2.8853900817779268f;

  for (int s = 0; s <= SEQL; ++s) {
    // h_s frags from OWN scratch (lgkmcnt orders vs prior writes; no barrier)
    const f16x8 ah0 = *(const f16x8*)(hscr + ro0);
    const f16x8 ah1 = *(const f16x8*)(hscr + ro1);

    if (s > 0) {
      // rel_{s-1}: D[p][batch], regs 0,1 valid on every quad -> lane-local.
      f32x4 p = __builtin_amdgcn_mfma_f32_16x16x32_f16(awp0, ah0, zC, 0, 0, 0);
      p = __builtin_amdgcn_mfma_f32_16x16x32_f16(awp1, ah1, p, 0, 0, 0);
      float u0 = p[0] + Gg0 + fmaf(ax, Sx0, ay * Sy0);
      float u1 = p[1] + Gg1 + fmaf(ax, Sx1, ay * Sy1);
      ax += u0;
      ay += u1;
      if (lane < 16) {
        float2 v;
        v.x = u0;
        v.y = u1;
        ((float2*)outp)[(size_t)(s - 1) * B_TOT + bb + lane] = v;
      }
      xf = build_x(u0, u1);
    }

    if (s < SEQL) {
      // per hidden-slice m: 12 weight frags from shared LDS, 12 MFMAs,
      // exp2 nonlinearity, scattered f16 writes to own scratch.
#pragma unroll
      for (int m = 0; m < 4; ++m) {
        const int hb = (16 * m + n) * 64;       // whh row base (f16 units)
        const int xb = (16 * m + n) * 32 + xsl; // wx row base
        f32x4 acc[4];
#pragma unroll
        for (int g = 0; g < 4; ++g) {
          const f16x8 w0 = *(const f16x8*)(whh + g * 4096 + hb + sl0);
          const f16x8 w1 = *(const f16x8*)(whh + g * 4096 + hb + sl1);
          const f16x8 w2 = *(const f16x8*)(wx + g * 2048 + xb);
          f32x4 a = __builtin_amdgcn_mfma_f32_16x16x32_f16(ah0, w0, zC,
                                                           0, 0, 0);
          a = __builtin_amdgcn_mfma_f32_16x16x32_f16(ah1, w1, a, 0, 0, 0);
          a = __builtin_amdgcn_mfma_f32_16x16x32_f16(xf, w2, a, 0, 0, 0);
          acc[g] = a;
        }
        const int c16 = 2 * m + (n >> 3);
        // acc0=-i*log2e, acc1=-f*log2e, acc2=2g*log2e, acc3=-o*log2e.
        // f32x2 pairs + pair-rcp (R11 algebra).
#pragma unroll
        for (int pr = 0; pr < 2; ++pr) {
          const int ra = 2 * pr, rb = 2 * pr + 1;
          f32x2 Av = {fexp2(acc[0][ra]), fexp2(acc[0][rb])};
          f32x2 Fv = {fexp2(acc[1][ra]), fexp2(acc[1][rb])};
          f32x2 Bv = {fexp2(acc[2][ra]), fexp2(acc[2][rb])};
          const f32x2 one = {1.f, 1.f};
          f32x2 t1 = Av + one;
          f32x2 t2 = Bv + one;
          f32x2 t3 = Fv + one;
          f32x2 t4 = Bv - one;
          f32x2 m1 = t1 * t2;
          f32x2 cs = {cst[m][ra], cst[m][rb]};
          f32x2 num = cs * m1 + t4 * t3;
          f32x2 den = m1 * t3;
          float Rc = frcp(den[0] * den[1]);
          float cc0 = num[0] * den[1] * Rc;
          float cc1 = num[1] * den[0] * Rc;
          cst[m][ra] = cc0;
          cst[m][rb] = cc1;
          f32x2 Cv = {fexp2(acc[3][ra]), fexp2(acc[3][rb])};
          f32x2 Dv = {fexp2(K2 * cc0), fexp2(K2 * cc1)};
          f32x2 hd = (Cv + one) * (Dv + one);
          f32x2 hnm = Dv - one;
          float Rh = frcp(hd[0] * hd[1]);
          float h0v = hnm[0] * hd[1] * Rh;
          float h1v = hnm[1] * hd[0] * Rh;
          const int bra = 4 * q + ra, brb = 4 * q + rb;
          hscr[wbase + bra * 64 + ((c16 ^ (bra & 7)) << 3) + (n & 7)] =
              (_Float16)h0v;
          hscr[wbase + brb * 64 + ((c16 ^ (brb & 7)) << 3) + (n & 7)] =
              (_Float16)h1v;
        }
      }
    }
  }
}

extern "C" void kernel_launch(void* const* d_in, const int* in_sizes, int n_in,
                              void* d_out, int out_size, void* d_ws,
                              size_t ws_size, hipStream_t stream) {
  (void)in_sizes; (void)n_in; (void)out_size; (void)ws_size;
  const float* tabs  = (const float*)d_in[0];
  const float* trel  = (const float*)d_in[1];
  const float* h0    = (const float*)d_in[2];
  const float* c0    = (const float*)d_in[3];
  const float* goals = (const float*)d_in[4];
  const float* Wih   = (const float*)d_in[5];
  const float* Whh   = (const float*)d_in[6];
  const float* bih   = (const float*)d_in[7];
  const float* bhh   = (const float*)d_in[8];
  const float* Wse   = (const float*)d_in[9];
  const float* bse   = (const float*)d_in[10];
  const float* Wh2p  = (const float*)d_in[11];
  const float* bh2p  = (const float*)d_in[12];
  const float* Wgoal = (const float*)d_in[13];
  const float* bgoal = (const float*)d_in[14];
  const float* Wabs  = (const float*)d_in[15];
  const float* babs  = (const float*)d_in[16];
  float* wsf = (float*)d_ws;

  setup_consts<<<dim3(1), dim3(128), 0, stream>>>(Wgoal, bgoal, Wh2p, bh2p,
                                                  Wabs, babs, wsf);
  lstm_mfma<<<dim3(B_TOT / (16 * WPB)), dim3(512), 0, stream>>>(
      tabs, trel, h0, c0, goals, Wih, Whh, bih, bhh, Wse, bse, Wh2p, wsf,
      (float*)d_out);
}